// Round 1
// baseline (341.166 us; speedup 1.0000x reference)
//
#include <hip/hip_runtime.h>
#include <hip/hip_bf16.h>

#define D 128
#define BI 64
#define BJ 64
#define NSPLIT 4
#define MARGIN 0.5f

// ---------------- prep: sq[i], init ap/an, zero out ----------------
// one wave per row (d=128 -> float2 per lane), block = 256 = 4 rows
__global__ void prep_kernel(const float* __restrict__ x,
                            float* __restrict__ sq,
                            unsigned* __restrict__ ap,
                            unsigned* __restrict__ an,
                            float* __restrict__ out, int n) {
    int tid = threadIdx.x;
    int row = blockIdx.x * 4 + (tid >> 6);
    int lane = tid & 63;
    if (row < n) {
        const float2* xr = (const float2*)(x + (size_t)row * D);
        float2 v = xr[lane];
        float s = v.x * v.x + v.y * v.y;
        #pragma unroll
        for (int o = 32; o > 0; o >>= 1) s += __shfl_xor(s, o, 64);
        if (lane == 0) {
            sq[row] = s;
            ap[row] = 0u;            // dist >= 0, so 0 is a valid -inf for max
            an[row] = 0x7F800000u;   // +inf bits
        }
    }
    if (blockIdx.x == 0 && tid == 0) *out = 0.0f;
}

// ---------------- main: fused dist + per-row hardest pos/neg ----------------
// 64x64 tile, 16x16 threads, 4x4 micro-tile, K=128 LDS-resident.
// LDS layout: row-major, float4-index swizzled: idx4 = row*32 + (kc ^ ((row>>2)&7))
//  -> staging writes conflict-free, fragment b128 reads <=2-way (free).
__launch_bounds__(256, 2)
__global__ void dist_kernel(const float* __restrict__ x,
                            const float* __restrict__ sq,
                            const int* __restrict__ tgt,
                            unsigned* __restrict__ ap,
                            unsigned* __restrict__ an, int n) {
    __shared__ float As[BI * D];
    __shared__ float Bs[BJ * D];
    __shared__ float sqA[BI], sqB[BJ];
    __shared__ int   tA[BI],  tB[BJ];

    const int tid = threadIdx.x;
    const int ti = tid >> 4;        // 0..15 -> rows 4*ti..4*ti+3
    const int tj = tid & 15;        // 0..15 -> cols 4*tj..4*tj+3
    const int i0 = blockIdx.x * BI;
    const int jtiles_per_split = (n / BJ) / NSPLIT;
    const int jt0 = blockIdx.y * jtiles_per_split;

    // ---- stage A tile (swizzled) ----
    {
        const float4* xg = (const float4*)(x + (size_t)i0 * D);
        float4* As4 = (float4*)As;
        #pragma unroll
        for (int it = 0; it < (BI * D / 4) / 256; ++it) {
            int idx4 = it * 256 + tid;       // float4 index in tile
            int row = idx4 >> 5;             // 32 float4 per row
            int kc  = idx4 & 31;
            As4[row * 32 + (kc ^ ((row >> 2) & 7))] = xg[idx4];
        }
        if (tid < BI) { sqA[tid] = sq[i0 + tid]; tA[tid] = tgt[i0 + tid]; }
    }
    __syncthreads();

    float si[4]; int li[4];
    #pragma unroll
    for (int r = 0; r < 4; ++r) { si[r] = sqA[4 * ti + r]; li[r] = tA[4 * ti + r]; }

    float lap[4] = {0.f, 0.f, 0.f, 0.f};
    float lan[4];
    #pragma unroll
    for (int r = 0; r < 4; ++r) lan[r] = __uint_as_float(0x7F800000u);

    const float4* As4c = (const float4*)As;
    const float4* Bs4c = (const float4*)Bs;

    for (int jt = jt0; jt < jt0 + jtiles_per_split; ++jt) {
        const int j0 = jt * BJ;
        __syncthreads();   // previous tile's reads done before overwrite
        {
            const float4* bg = (const float4*)(x + (size_t)j0 * D);
            float4* Bs4 = (float4*)Bs;
            #pragma unroll
            for (int it = 0; it < (BJ * D / 4) / 256; ++it) {
                int idx4 = it * 256 + tid;
                int row = idx4 >> 5;
                int kc  = idx4 & 31;
                Bs4[row * 32 + (kc ^ ((row >> 2) & 7))] = bg[idx4];
            }
            if (tid < BJ) { sqB[tid] = sq[j0 + tid]; tB[tid] = tgt[j0 + tid]; }
        }
        __syncthreads();

        float acc[4][4] = {};
        #pragma unroll 4
        for (int kc = 0; kc < 32; ++kc) {
            float4 a[4], b[4];
            #pragma unroll
            for (int r = 0; r < 4; ++r)
                a[r] = As4c[(4 * ti + r) * 32 + (kc ^ (ti & 7))];
            #pragma unroll
            for (int c = 0; c < 4; ++c)
                b[c] = Bs4c[(4 * tj + c) * 32 + (kc ^ (tj & 7))];
            #pragma unroll
            for (int r = 0; r < 4; ++r)
                #pragma unroll
                for (int c = 0; c < 4; ++c) {
                    acc[r][c] = fmaf(a[r].x, b[c].x, acc[r][c]);
                    acc[r][c] = fmaf(a[r].y, b[c].y, acc[r][c]);
                    acc[r][c] = fmaf(a[r].z, b[c].z, acc[r][c]);
                    acc[r][c] = fmaf(a[r].w, b[c].w, acc[r][c]);
                }
        }

        // epilogue: dist + masked max/min
        #pragma unroll
        for (int r = 0; r < 4; ++r) {
            #pragma unroll
            for (int c = 0; c < 4; ++c) {
                int gj = 4 * tj + c;
                float d2 = si[r] + sqB[gj] - 2.0f * acc[r][c];
                d2 = fmaxf(d2, 0.0f);
                if (li[r] == tB[gj]) lap[r] = fmaxf(lap[r], d2);
                else                 lan[r] = fminf(lan[r], d2);
            }
        }
    }

    // reduce across the 16 tj-lanes sharing each row (contiguous lanes in wave)
    #pragma unroll
    for (int r = 0; r < 4; ++r) {
        float p = lap[r], q = lan[r];
        #pragma unroll
        for (int o = 1; o < 16; o <<= 1) {
            p = fmaxf(p, __shfl_xor(p, o, 64));
            q = fminf(q, __shfl_xor(q, o, 64));
        }
        if (tj == 0) {
            int gi = i0 + 4 * ti + r;
            atomicMax(&ap[gi], __float_as_uint(p));
            atomicMin(&an[gi], __float_as_uint(q));
        }
    }
}

// ---------------- final: sum relu(ap - an + margin) ----------------
__global__ void final_kernel(const unsigned* __restrict__ ap,
                             const unsigned* __restrict__ an,
                             float* __restrict__ out, int n) {
    int i = blockIdx.x * blockDim.x + threadIdx.x;
    float v = 0.f;
    if (i < n) {
        float p = __uint_as_float(ap[i]);
        float q = __uint_as_float(an[i]);
        v = fmaxf(p - q + MARGIN, 0.0f);
        if (!(v > 0.f)) v = 0.f;   // handles -inf/NaN edge (no negatives case)
    }
    #pragma unroll
    for (int o = 32; o > 0; o >>= 1) v += __shfl_xor(v, o, 64);
    __shared__ float ws[4];
    int lane = threadIdx.x & 63, w = threadIdx.x >> 6;
    if (lane == 0) ws[w] = v;
    __syncthreads();
    if (threadIdx.x == 0) atomicAdd(out, ws[0] + ws[1] + ws[2] + ws[3]);
}

extern "C" void kernel_launch(void* const* d_in, const int* in_sizes, int n_in,
                              void* d_out, int out_size, void* d_ws, size_t ws_size,
                              hipStream_t stream) {
    const float* x   = (const float*)d_in[0];
    const int*   tgt = (const int*)d_in[1];
    float* out = (float*)d_out;
    const int n = in_sizes[1];              // 8192

    float*    sq = (float*)d_ws;
    unsigned* ap = (unsigned*)((char*)d_ws + (size_t)n * sizeof(float));
    unsigned* an = ap + n;

    prep_kernel<<<n / 4, 256, 0, stream>>>(x, sq, ap, an, out, n);
    dim3 grid(n / BI, NSPLIT);
    dist_kernel<<<grid, 256, 0, stream>>>(x, sq, tgt, ap, an, n);
    final_kernel<<<n / 256, 256, 0, stream>>>(ap, an, out, n);
}

// Round 2
// 91.150 us; speedup vs baseline: 3.7429x; 3.7429x over previous
//
#include <hip/hip_runtime.h>
#include <hip/hip_bf16.h>

#define D 128
#define MARGIN 0.5f
#define LDB 136   // padded LDS row length (bf16 elems): 272 B, breaks bank alignment

typedef __attribute__((ext_vector_type(8))) short bf16x8;
typedef __attribute__((ext_vector_type(4))) float f32x4;

// ---------------- prep: bf16 convert + sq + init ----------------
// one wave per row (d=128 -> float2/lane), block = 256 = 4 rows
__global__ void prep_kernel(const float* __restrict__ x,
                            float* __restrict__ sq,
                            unsigned* __restrict__ ap,
                            unsigned* __restrict__ an,
                            __hip_bfloat16* __restrict__ xb,
                            float* __restrict__ out, int n) {
    int tid = threadIdx.x;
    int row = blockIdx.x * 4 + (tid >> 6);
    int lane = tid & 63;
    const float2* xr = (const float2*)(x + (size_t)row * D);
    float2 v = xr[lane];
    __hip_bfloat162 b2;
    b2.x = __float2bfloat16(v.x);
    b2.y = __float2bfloat16(v.y);
    ((__hip_bfloat162*)(xb + (size_t)row * D))[lane] = b2;
    float s = v.x * v.x + v.y * v.y;
    #pragma unroll
    for (int o = 32; o > 0; o >>= 1) s += __shfl_xor(s, o, 64);
    if (lane == 0) {
        sq[row] = s;
        ap[row] = 0u;            // dist >= 0 -> 0 is valid -inf for max
        an[row] = 0x7F800000u;   // +inf bits
    }
    if (blockIdx.x == 0 && tid == 0) *out = 0.0f;
}

// ---------------- gram: MFMA dist + fused hardest pos/neg ----------------
// 128x128 output tile / block, 4 waves in 2x2, each wave 64x64 via 4x4 mfma
// tiles. K=128 LDS-resident; A-frags hoisted to regs for all 8 j-iters.
__launch_bounds__(256, 2)
__global__ void gram_kernel(const __hip_bfloat16* __restrict__ xb,
                            const float* __restrict__ sq,
                            const int* __restrict__ tgt,
                            unsigned* __restrict__ ap,
                            unsigned* __restrict__ an, int n) {
    __shared__ __align__(16) __hip_bfloat16 Asb[128 * LDB];
    __shared__ __align__(16) __hip_bfloat16 Bsb[128 * LDB];
    __shared__ float sqB[128];
    __shared__ int   tgtB[128];

    const int tid  = threadIdx.x;
    const int wid  = tid >> 6;
    const int lane = tid & 63;
    const int quad = lane >> 4;
    const int l    = lane & 15;
    const int w_mi = wid >> 1;     // wave row (0/1)
    const int w_nj = wid & 1;      // wave col (0/1)
    const int i0   = blockIdx.x * 128;

    // ---- stage A tile (128 rows x 128 bf16), coalesced 16B chunks ----
    {
        const float4* src = (const float4*)(xb + (size_t)i0 * D);
        #pragma unroll
        for (int it = 0; it < 8; ++it) {
            int cid = it * 256 + tid;          // 16B-chunk id, 16 per row
            int r = cid >> 4, c = cid & 15;
            *(float4*)(&Asb[r * LDB + c * 8]) = src[r * 16 + c];
        }
    }
    __syncthreads();

    // ---- hoist A fragments: [mt][ks], lane holds A[m=l][k=quad*8+j] ----
    bf16x8 afrag[4][4];
    #pragma unroll
    for (int mt = 0; mt < 4; ++mt) {
        int r = w_mi * 64 + mt * 16 + l;
        #pragma unroll
        for (int ks = 0; ks < 4; ++ks)
            afrag[mt][ks] = *(const bf16x8*)(&Asb[r * LDB + ks * 32 + quad * 8]);
    }

    // row labels for this lane's output rows (C/D: row = quad*4+reg)
    int li[4][4];
    #pragma unroll
    for (int mt = 0; mt < 4; ++mt)
        #pragma unroll
        for (int reg = 0; reg < 4; ++reg)
            li[mt][reg] = tgt[i0 + w_mi * 64 + mt * 16 + quad * 4 + reg];

    // running hardest pos/neg in t-space (t = sq_j - 2*dot); add sq_i at end
    float lap[4][4], lan[4][4];
    #pragma unroll
    for (int mt = 0; mt < 4; ++mt)
        #pragma unroll
        for (int reg = 0; reg < 4; ++reg) { lap[mt][reg] = -1e30f; lan[mt][reg] = 1e30f; }

    for (int jj = 0; jj < 8; ++jj) {
        const int j0 = (blockIdx.y * 8 + jj) * 128;
        __syncthreads();   // prev iter's B-frag reads done
        {
            const float4* src = (const float4*)(xb + (size_t)j0 * D);
            #pragma unroll
            for (int it = 0; it < 8; ++it) {
                int cid = it * 256 + tid;
                int r = cid >> 4, c = cid & 15;
                *(float4*)(&Bsb[r * LDB + c * 8]) = src[r * 16 + c];
            }
            if (tid < 128) { sqB[tid] = sq[j0 + tid]; tgtB[tid] = tgt[j0 + tid]; }
        }
        __syncthreads();

        float sjv[4]; int tjv[4];
        #pragma unroll
        for (int jt = 0; jt < 4; ++jt) {
            int c = w_nj * 64 + jt * 16 + l;
            sjv[jt] = sqB[c]; tjv[jt] = tgtB[c];
        }

        f32x4 acc[4][4];
        #pragma unroll
        for (int mt = 0; mt < 4; ++mt)
            #pragma unroll
            for (int jt = 0; jt < 4; ++jt)
                acc[mt][jt] = (f32x4){0.f, 0.f, 0.f, 0.f};

        #pragma unroll
        for (int ks = 0; ks < 4; ++ks) {
            bf16x8 bfr[4];
            #pragma unroll
            for (int jt = 0; jt < 4; ++jt) {
                int r = w_nj * 64 + jt * 16 + l;
                bfr[jt] = *(const bf16x8*)(&Bsb[r * LDB + ks * 32 + quad * 8]);
            }
            #pragma unroll
            for (int mt = 0; mt < 4; ++mt)
                #pragma unroll
                for (int jt = 0; jt < 4; ++jt)
                    acc[mt][jt] = __builtin_amdgcn_mfma_f32_16x16x32_bf16(
                        afrag[mt][ks], bfr[jt], acc[mt][jt], 0, 0, 0);
        }

        // epilogue: t = sq_j - 2*dot; masked max/min into lap/lan
        #pragma unroll
        for (int mt = 0; mt < 4; ++mt)
            #pragma unroll
            for (int jt = 0; jt < 4; ++jt)
                #pragma unroll
                for (int reg = 0; reg < 4; ++reg) {
                    float t = fmaf(-2.0f, acc[mt][jt][reg], sjv[jt]);
                    bool same = (li[mt][reg] == tjv[jt]);
                    lap[mt][reg] = fmaxf(lap[mt][reg], same ? t : -1e30f);
                    lan[mt][reg] = fminf(lan[mt][reg], same ? 1e30f : t);
                }
    }

    // reduce across the 16 column-lanes (within quad), then atomics
    #pragma unroll
    for (int mt = 0; mt < 4; ++mt)
        #pragma unroll
        for (int reg = 0; reg < 4; ++reg) {
            float p = lap[mt][reg], q = lan[mt][reg];
            #pragma unroll
            for (int o = 1; o < 16; o <<= 1) {
                p = fmaxf(p, __shfl_xor(p, o, 64));
                q = fminf(q, __shfl_xor(q, o, 64));
            }
            if (l == mt * 4 + reg) {   // distribute the 16 rows across 16 lanes
                int gi = i0 + w_mi * 64 + mt * 16 + quad * 4 + reg;
                float s = sq[gi];
                atomicMax(&ap[gi], __float_as_uint(fmaxf(s + p, 0.0f)));
                atomicMin(&an[gi], __float_as_uint(fmaxf(s + q, 0.0f)));
            }
        }
}

// ---------------- final: sum relu(ap - an + margin) ----------------
__global__ void final_kernel(const unsigned* __restrict__ ap,
                             const unsigned* __restrict__ an,
                             float* __restrict__ out, int n) {
    int i = blockIdx.x * blockDim.x + threadIdx.x;
    float v = 0.f;
    if (i < n) {
        float p = __uint_as_float(ap[i]);
        float q = __uint_as_float(an[i]);
        v = fmaxf(p - q + MARGIN, 0.0f);
    }
    #pragma unroll
    for (int o = 32; o > 0; o >>= 1) v += __shfl_xor(v, o, 64);
    __shared__ float ws[4];
    int lane = threadIdx.x & 63, w = threadIdx.x >> 6;
    if (lane == 0) ws[w] = v;
    __syncthreads();
    if (threadIdx.x == 0) atomicAdd(out, ws[0] + ws[1] + ws[2] + ws[3]);
}

extern "C" void kernel_launch(void* const* d_in, const int* in_sizes, int n_in,
                              void* d_out, int out_size, void* d_ws, size_t ws_size,
                              hipStream_t stream) {
    const float* x   = (const float*)d_in[0];
    const int*   tgt = (const int*)d_in[1];
    float* out = (float*)d_out;
    const int n = in_sizes[1];              // 8192

    float*          sq = (float*)d_ws;
    unsigned*       ap = (unsigned*)((char*)d_ws + (size_t)n * 4);
    unsigned*       an = ap + n;
    __hip_bfloat16* xb = (__hip_bfloat16*)((char*)d_ws + (size_t)n * 12);

    prep_kernel<<<n / 4, 256, 0, stream>>>(x, sq, ap, an, xb, out, n);
    dim3 grid(n / 128, 8);
    gram_kernel<<<grid, 256, 0, stream>>>(xb, sq, tgt, ap, an, n);
    final_kernel<<<n / 256, 256, 0, stream>>>(ap, an, out, n);
}